// Round 5
// baseline (339.573 us; speedup 1.0000x reference)
//
#include <hip/hip_runtime.h>

// DIAGNOSTIC ROUND: round-1 kernel (best: 298 us) launched TWICE.
// dur_us - 298 ~= duration of one L3-warm launch; separates
// "HBM-bound, near ceiling" from "latency-bound, big headroom".
//
// burst:   (nd=32, c=3, 128, 128) fp32
// kernels: (nd=32, r=4, 5, 5, 128, 128) fp32
// out:     (nd=32, c=3, 256, 256) fp32 (pixel-shuffle s=2)
#define HH 128
#define WW 128
#define CC 3
#define RR 4
#define KK 5
#define ND 32
#define HW (HH*WW)

__global__ __launch_bounds__(256) void adaptive_conv_ps(
    const float* __restrict__ burst,
    const float* __restrict__ kern,
    float* __restrict__ out)
{
    int t  = blockIdx.x * blockDim.x + threadIdx.x;
    int w  = t & (WW - 1);
    int h  = (t >> 7) & (HH - 1);
    int nd = t >> 14;

    const float* bptr = burst + (size_t)nd * CC * HW;
    const float* kptr = kern  + (size_t)nd * RR * KK * KK * HW + h * WW + w;

    float patch[CC][KK * KK];
#pragma unroll
    for (int c = 0; c < CC; ++c) {
#pragma unroll
        for (int i = 0; i < KK; ++i) {
            int  y  = h + i - 2;
            bool yv = (unsigned)y < (unsigned)HH;
#pragma unroll
            for (int j = 0; j < KK; ++j) {
                int  x = w + j - 2;
                bool v = yv && ((unsigned)x < (unsigned)WW);
                patch[c][i * KK + j] = v ? bptr[c * HW + y * WW + x] : 0.0f;
            }
        }
    }

    float acc[CC][RR];
#pragma unroll
    for (int c = 0; c < CC; ++c)
#pragma unroll
        for (int r = 0; r < RR; ++r)
            acc[c][r] = 0.0f;

#pragma unroll
    for (int r = 0; r < RR; ++r) {
#pragma unroll
        for (int ij = 0; ij < KK * KK; ++ij) {
            float kv = kptr[(size_t)(r * KK * KK + ij) * HW];
#pragma unroll
            for (int c = 0; c < CC; ++c)
                acc[c][r] += kv * patch[c][ij];
        }
    }

#pragma unroll
    for (int c = 0; c < CC; ++c) {
#pragma unroll
        for (int si = 0; si < 2; ++si) {
            float2 v = make_float2(acc[c][si * 2 + 0], acc[c][si * 2 + 1]);
            float* o = out + (((size_t)(nd * CC + c) * (2 * HH) + (2 * h + si)) * (2 * WW)) + 2 * w;
            *(float2*)o = v;
        }
    }
}

extern "C" void kernel_launch(void* const* d_in, const int* in_sizes, int n_in,
                              void* d_out, int out_size, void* d_ws, size_t ws_size,
                              hipStream_t stream) {
    const float* burst = (const float*)d_in[0];
    const float* kern  = (const float*)d_in[1];
    float* out = (float*)d_out;

    const int total = ND * HH * WW;
    const int block = 256;
    const int grid  = total / block;
    // Launch twice: second launch is L3-warm (inputs ~230 MB < 256 MB L3).
    adaptive_conv_ps<<<grid, block, 0, stream>>>(burst, kern, out);
    adaptive_conv_ps<<<grid, block, 0, stream>>>(burst, kern, out);
}

// Round 6
// 294.464 us; speedup vs baseline: 1.1532x; 1.1532x over previous
//
#include <hip/hip_runtime.h>

// Best structure (round 1): 1 px/thread, 2048 blocks, no LDS, no barrier.
// Diagnostic (round 5) showed: L3-warm launch = 41.5 us (~5.7 TB/s effective),
// cold = ~48 us vs 35 us pure-stream floor -> BW/latency-bound, near ceiling.
// This round: + nontemporal hint on the read-once 200 MB kernel stream.
//
// burst:   (nd=32, c=3, 128, 128) fp32
// kernels: (nd=32, r=4, 5, 5, 128, 128) fp32
// out:     (nd=32, c=3, 256, 256) fp32 (pixel-shuffle s=2)
#define HH 128
#define WW 128
#define CC 3
#define RR 4
#define KK 5
#define ND 32
#define HW (HH*WW)

__global__ __launch_bounds__(256) void adaptive_conv_ps(
    const float* __restrict__ burst,
    const float* __restrict__ kern,
    float* __restrict__ out)
{
    int t  = blockIdx.x * blockDim.x + threadIdx.x;
    int w  = t & (WW - 1);
    int h  = (t >> 7) & (HH - 1);
    int nd = t >> 14;

    const float* bptr = burst + (size_t)nd * CC * HW;
    const float* kptr = kern  + (size_t)nd * RR * KK * KK * HW + h * WW + w;

    // 3x5x5 burst patch (zero-padded borders); burst slice is L2-hot (196 KB/nd).
    float patch[CC][KK * KK];
#pragma unroll
    for (int c = 0; c < CC; ++c) {
#pragma unroll
        for (int i = 0; i < KK; ++i) {
            int  y  = h + i - 2;
            bool yv = (unsigned)y < (unsigned)HH;
#pragma unroll
            for (int j = 0; j < KK; ++j) {
                int  x = w + j - 2;
                bool v = yv && ((unsigned)x < (unsigned)WW);
                patch[c][i * KK + j] = v ? bptr[c * HW + y * WW + x] : 0.0f;
            }
        }
    }

    float acc[CC][RR];
#pragma unroll
    for (int c = 0; c < CC; ++c)
#pragma unroll
        for (int r = 0; r < RR; ++r)
            acc[c][r] = 0.0f;

    // Stream 100 per-pixel kernel taps, coalesced along w; read-once ->
    // nontemporal (don't allocate in L1/L2, keep burst/out lines resident).
#pragma unroll
    for (int r = 0; r < RR; ++r) {
#pragma unroll
        for (int ij = 0; ij < KK * KK; ++ij) {
            float kv = __builtin_nontemporal_load(
                kptr + (size_t)(r * KK * KK + ij) * HW);
#pragma unroll
            for (int c = 0; c < CC; ++c)
                acc[c][r] += kv * patch[c][ij];
        }
    }

    // Pixel-shuffle store: out[nd, c, 2h+si, 2w+sj] = acc[c][si*2+sj]
#pragma unroll
    for (int c = 0; c < CC; ++c) {
#pragma unroll
        for (int si = 0; si < 2; ++si) {
            float2 v = make_float2(acc[c][si * 2 + 0], acc[c][si * 2 + 1]);
            float* o = out + (((size_t)(nd * CC + c) * (2 * HH) + (2 * h + si)) * (2 * WW)) + 2 * w;
            *(float2*)o = v;
        }
    }
}

extern "C" void kernel_launch(void* const* d_in, const int* in_sizes, int n_in,
                              void* d_out, int out_size, void* d_ws, size_t ws_size,
                              hipStream_t stream) {
    const float* burst = (const float*)d_in[0];
    const float* kern  = (const float*)d_in[1];
    float* out = (float*)d_out;

    const int total = ND * HH * WW;          // 524288 threads, 1 px/thread
    adaptive_conv_ps<<<total / 256, 256, 0, stream>>>(burst, kern, out);
}